// Round 4
// baseline (81.512 us; speedup 1.0000x reference)
//
#include <hip/hip_runtime.h>

typedef unsigned short u16;
typedef __bf16 bf16x8 __attribute__((ext_vector_type(8)));
typedef float f32x4 __attribute__((ext_vector_type(4)));

#define GLD_LDS(gptr, lptr) \
  __builtin_amdgcn_global_load_lds((const __attribute__((address_space(1))) void*)(gptr), \
                                   (__attribute__((address_space(3))) void*)(lptr), 16, 0, 0)

template<int N> __device__ __forceinline__ void waitcnt_vm() {
  asm volatile("s_waitcnt vmcnt(%0)" :: "n"(N) : "memory");
}

__device__ __forceinline__ u16 f2b(float f) {
  union { __bf16 h; u16 u; } v; v.h = (__bf16)f; return v.u;
}
__device__ __forceinline__ float elu1(float v) {
  return v > 0.f ? v : (__expf(v) - 1.f);
}

// ---------------- fused convert + route kernel ----------------
// blocks [0,128):    W_in [512][1024] f32 -> o0 [1024][512] bf16
// blocks [128,1152): W1 [8][1024][512]    -> o1 [8][512][1024]
// blocks [1152,1216):W2 [8][512][64]      -> o2 [8][64][512]
// blocks [1216,3264): x [8192*512] f32 -> bf16 straight copy
// block 3264: routing
__global__ __launch_bounds__(256) void wcvt(const float* __restrict__ W_in,
                                            const float* __restrict__ W1,
                                            const float* __restrict__ W2,
                                            const float* __restrict__ x,
                                            const int* __restrict__ cat,
                                            u16* __restrict__ o0, u16* __restrict__ o1,
                                            u16* __restrict__ o2, u16* __restrict__ ox,
                                            int* __restrict__ list, int* __restrict__ off) {
  const int bid = blockIdx.x, tid = threadIdx.x;
  if (bid == 3264) {  // routing
    __shared__ int cnt[8], cur[8], offs[9];
    if (tid < 8) cnt[tid] = 0;
    __syncthreads();
    for (int i = tid; i < 8192; i += 256) atomicAdd(&cnt[cat[i]], 1);
    __syncthreads();
    if (tid == 0) {
      int s = 0;
      for (int e2 = 0; e2 < 8; e2++) { offs[e2] = s; s += cnt[e2]; }
      offs[8] = s;
    }
    __syncthreads();
    if (tid < 8) cur[tid] = offs[tid];
    if (tid < 9) off[tid] = offs[tid];
    __syncthreads();
    for (int i = tid; i < 8192; i += 256) {
      int c = cat[i];
      list[atomicAdd(&cur[c], 1)] = i;
    }
    return;
  }
  if (bid >= 1216) {
    const size_t base = (size_t)(bid - 1216) * 2048 + (size_t)tid * 8;
    float4 v0 = *reinterpret_cast<const float4*>(x + base);
    float4 v1 = *reinterpret_cast<const float4*>(x + base + 4);
    ushort4 a, b;
    a.x = f2b(v0.x); a.y = f2b(v0.y); a.z = f2b(v0.z); a.w = f2b(v0.w);
    b.x = f2b(v1.x); b.y = f2b(v1.y); b.z = f2b(v1.z); b.w = f2b(v1.w);
    *reinterpret_cast<ushort4*>(ox + base) = a;
    *reinterpret_cast<ushort4*>(ox + base + 4) = b;
    return;
  }
  const float* src; u16* dst; int R, C, tr, tc; size_t zoff;
  if (bid < 128) {
    src = W_in; dst = o0; R = 512; C = 1024; tr = bid >> 4; tc = bid & 15; zoff = 0;
  } else if (bid < 1152) {
    int t = bid - 128; int z = t >> 7, rem = t & 127;
    src = W1; dst = o1; R = 1024; C = 512; tr = rem >> 3; tc = rem & 7;
    zoff = (size_t)z * R * C;
  } else {
    int t = bid - 1152; int z = t >> 3;
    src = W2; dst = o2; R = 512; C = 64; tr = t & 7; tc = 0;
    zoff = (size_t)z * R * C;
  }
  __shared__ float tbuf[64][65];
  const float* sp = src + zoff + (size_t)(tr * 64) * C + tc * 64;
#pragma unroll
  for (int i = 0; i < 4; i++) {
    const int rr = (tid >> 4) + i * 16, f = tid & 15;
    float4 v = *reinterpret_cast<const float4*>(sp + (size_t)rr * C + f * 4);
    tbuf[rr][f * 4 + 0] = v.x; tbuf[rr][f * 4 + 1] = v.y;
    tbuf[rr][f * 4 + 2] = v.z; tbuf[rr][f * 4 + 3] = v.w;
  }
  __syncthreads();
  u16* dp = dst + zoff + (size_t)(tc * 64) * R + tr * 64;
#pragma unroll
  for (int i = 0; i < 4; i++) {
    const int u = tid + i * 256;
    const int c = u >> 4, rq = u & 15;
    ushort4 w;
    w.x = f2b(tbuf[rq * 4 + 0][c]); w.y = f2b(tbuf[rq * 4 + 1][c]);
    w.z = f2b(tbuf[rq * 4 + 2][c]); w.w = f2b(tbuf[rq * 4 + 3][c]);
    *reinterpret_cast<ushort4*>(dp + (size_t)c * R + rq * 4) = w;
  }
}

// ---------------- unified pipelined GEMM ----------------
// BM=64, BK=32, 4 waves (2x2), 3-buffer depth-2 prefetch, counted vmcnt.
// LAYER 1: dense rows, bf16 out + ELU.
// LAYER 2: rows gathered via list, compact bf16 out + ELU.
// LAYER 3: compact rows in, f32 out scattered via list, no activation.

template<int LAYER, int BN, int K, int N>
__global__ __launch_bounds__(256, 4) void gemm_t(
    const u16* __restrict__ A, const u16* __restrict__ Bw,
    const float* __restrict__ bias,
    const int* __restrict__ list, const int* __restrict__ off,
    u16* __restrict__ outb, float* __restrict__ outf) {
  __shared__ alignas(16) u16 As[3][64 * 32];
  __shared__ alignas(16) u16 Bs[3][BN * 32];

  const int tid = threadIdx.x;
  const int wave = tid >> 6, lane = tid & 63;

  int e = 0, start = 0, cnt = 0, rowbase;
  if constexpr (LAYER == 1) {
    rowbase = blockIdx.x * 64;
  } else {
    int t = blockIdx.x;
    int found = -1;
    for (e = 0; e < 8; e++) {
      int tiles = (off[e + 1] - off[e] + 63) >> 6;
      if (t < tiles) { found = e; break; }
      t -= tiles;
    }
    if (found < 0) return;
    start = off[e];
    cnt = off[e + 1] - start;
    rowbase = t * 64;
  }
  const int col0 = blockIdx.y * BN;

  // staging: thread t stages (row = t>>2, chunk = t&3); source chunk XOR-swizzled
  const int srow = tid >> 2, skc = tid & 3;
  const int kxs = (skc ^ (srow & 3)) * 8;

  const u16* a_src;
  if constexpr (LAYER == 1) {
    a_src = A + (size_t)(rowbase + srow) * K + kxs;
  } else if constexpr (LAYER == 2) {
    int slot = rowbase + srow;
    int gr = list[start + min(slot, cnt - 1)];
    a_src = A + (size_t)gr * K + kxs;
  } else {
    int slot = rowbase + srow;
    a_src = A + (size_t)(start + min(slot, cnt - 1)) * K + kxs;
  }
  const u16* Bbase = Bw + (LAYER == 1 ? (size_t)0 : (size_t)e * N * K);
  const u16* b_src0 = Bbase + (size_t)(col0 + srow) * K + kxs;
  const u16* b_src1 = Bbase + (size_t)(col0 + 64 + srow) * K + kxs;

  const int wbase = wave * 64 * 8;  // wave-uniform LDS dest base (elems)

  constexpr int NR = BN / 32;
  constexpr int S = (BN == 128) ? 3 : 2;  // gld_lds per thread per stage
  const int wy = wave & 1, wx = wave >> 1;
  const int fr = lane & 15, kg = lane >> 4;
  const int kx = (kg ^ (fr & 3)) * 8;
  const int ar0 = (wy * 32 + fr) * 32 + kx;
  const int br0 = (wx * (BN / 2) + fr) * 32 + kx;

  f32x4 acc[2][NR] = {};

  auto STAGE = [&](int t, int buf) {
    const int kt = t * 32;
    GLD_LDS(a_src + kt, &As[buf][wbase]);
    GLD_LDS(b_src0 + kt, &Bs[buf][wbase]);
    if constexpr (BN == 128) GLD_LDS(b_src1 + kt, &Bs[buf][2048 + wbase]);
  };
  auto COMPUTE = [&](int buf) {
    bf16x8 af[2], bfv[NR];
#pragma unroll
    for (int m = 0; m < 2; m++) af[m] = *(const bf16x8*)&As[buf][ar0 + m * 16 * 32];
#pragma unroll
    for (int n = 0; n < NR; n++) bfv[n] = *(const bf16x8*)&Bs[buf][br0 + n * 16 * 32];
#pragma unroll
    for (int m = 0; m < 2; m++)
#pragma unroll
      for (int n = 0; n < NR; n++)
        acc[m][n] = __builtin_amdgcn_mfma_f32_16x16x32_bf16(af[m], bfv[n], acc[m][n], 0, 0, 0);
  };

  constexpr int NK = K / 32;  // >= 3 always here
  // prologue: two tiles in flight
  STAGE(0, 0);
  STAGE(1, 1);
  int buf = 0;
  // main: iter t waits STAGE(t), keeps STAGE(t+1), STAGE(t+2) in flight
  for (int t = 0; t < NK - 2; ++t) {
    int bnxt = buf + 2; if (bnxt >= 3) bnxt -= 3;
    STAGE(t + 2, bnxt);
    waitcnt_vm<2 * S>();                 // STAGE(t) complete (2 newer stages in flight)
    __builtin_amdgcn_s_barrier();        // buf[t%3] fully staged by all waves
    COMPUTE(buf);
    __builtin_amdgcn_s_barrier();        // all reads done -> next iter may overwrite
    buf = (buf == 2) ? 0 : buf + 1;
  }
  // t = NK-2: one stage in flight
  waitcnt_vm<S>();
  __builtin_amdgcn_s_barrier();
  COMPUTE(buf);
  __builtin_amdgcn_s_barrier();
  buf = (buf == 2) ? 0 : buf + 1;
  // t = NK-1: last
  waitcnt_vm<0>();
  __builtin_amdgcn_s_barrier();
  COMPUTE(buf);

  // epilogue
#pragma unroll
  for (int n = 0; n < NR; n++) {
    const int col = col0 + wx * (BN / 2) + n * 16 + fr;
    const float bc = bias[(LAYER == 1 ? 0 : e * N) + col];
#pragma unroll
    for (int m = 0; m < 2; m++) {
      const int rloc = wy * 32 + m * 16 + kg * 4;
#pragma unroll
      for (int j = 0; j < 4; j++) {
        const float v = acc[m][n][j] + bc;
        if constexpr (LAYER == 1) {
          outb[(size_t)(rowbase + rloc + j) * N + col] = f2b(elu1(v));
        } else if constexpr (LAYER == 2) {
          const int slot = rowbase + rloc + j;
          if (slot < cnt) outb[(size_t)(start + slot) * N + col] = f2b(elu1(v));
        } else {
          const int slot = rowbase + rloc + j;
          if (slot < cnt) outf[(size_t)list[start + slot] * N + col] = v;
        }
      }
    }
  }
}

// ---------------- launch ----------------

extern "C" void kernel_launch(void* const* d_in, const int* in_sizes, int n_in,
                              void* d_out, int out_size, void* d_ws, size_t ws_size,
                              hipStream_t stream) {
  const float* x    = (const float*)d_in[0];
  const int*   cat  = (const int*)d_in[1];
  const float* W_in = (const float*)d_in[2];
  const float* b_in = (const float*)d_in[3];
  const float* W1   = (const float*)d_in[4];
  const float* b1   = (const float*)d_in[5];
  const float* W2   = (const float*)d_in[6];
  const float* b2   = (const float*)d_in[7];
  float* out = (float*)d_out;

  char* p = (char*)d_ws;
  u16* xb   = (u16*)p; p += (size_t)8192 * 512 * 2;    // 8 MB
  u16* midb = (u16*)p; p += (size_t)8192 * 1024 * 2;   // 16 MB
  u16* hb   = (u16*)p; p += (size_t)8192 * 512 * 2;    // 8 MB
  u16* wtin = (u16*)p; p += (size_t)1024 * 512 * 2;    // 1 MB
  u16* w1t  = (u16*)p; p += (size_t)8 * 512 * 1024 * 2;// 8 MB
  u16* w2t  = (u16*)p; p += (size_t)8 * 64 * 512 * 2;  // 0.5 MB
  int* list = (int*)p; p += (size_t)8192 * 4;          // 32 KB
  int* off  = (int*)p; p += 64;

  // conversions + routing in one launch
  wcvt<<<3265, 256, 0, stream>>>(W_in, W1, W2, x, cat, wtin, w1t, w2t, xb, list, off);

  // layer 1: [8192,512] @ [512,1024] -> midb
  gemm_t<1, 128, 512, 1024><<<dim3(128, 8), 256, 0, stream>>>(
      xb, wtin, b_in, nullptr, nullptr, midb, nullptr);
  // layer 2 grouped: [cnt_e,1024] @ [1024,512] -> hb (compact)
  gemm_t<2, 128, 1024, 512><<<dim3(136, 4), 256, 0, stream>>>(
      midb, w1t, b1, list, off, hb, nullptr);
  // layer 3 grouped: [cnt_e,512] @ [512,64] -> out (scattered)
  gemm_t<3, 64, 512, 64><<<dim3(136, 1), 256, 0, stream>>>(
      hb, w2t, b2, list, off, nullptr, out);
}